// Round 3
// baseline (284.089 us; speedup 1.0000x reference)
//
#include <hip/hip_runtime.h>
#include <cstdint>
#include <cstddef>

// Problem constants
#define M_DIM 8192   // batch
#define N_DIM 256    // shared rows (distinct output cols)
#define K_DIM 4096   // in_features
#define OUT_F 4096   // out_features = 16 * N_DIM
// Fused GEMM tiling
#define BM 32        // m-rows per block
#define BN 128       // n-half per block -> grid (256,2) = 512 blocks = 2/CU
#define BK 64        // k per tile
#define NTH 256      // 4 waves; wave w owns 32m x 32n via mfma_f32_32x32x16_f16
#define NKT (K_DIM / BK)  // 64

typedef float    float4_ __attribute__((ext_vector_type(4)));
typedef float    f32x16  __attribute__((ext_vector_type(16)));
typedef _Float16 half8   __attribute__((ext_vector_type(8)));

// ---------------------------------------------------------------------------
// Kernel 1: convert shared_weights fp32 -> f16 (2 MB, stays L2-resident)
// ---------------------------------------------------------------------------
__global__ __launch_bounds__(256) void convert_w_kernel(const float* __restrict__ w,
                                                        _Float16* __restrict__ wh) {
  int i = (blockIdx.x * 256 + threadIdx.x) * 8;
  float4_ f0 = *(const float4_*)(w + i);
  float4_ f1 = *(const float4_*)(w + i + 4);
  half8 h;
  h[0] = (_Float16)f0[0]; h[1] = (_Float16)f0[1];
  h[2] = (_Float16)f0[2]; h[3] = (_Float16)f0[3];
  h[4] = (_Float16)f1[0]; h[5] = (_Float16)f1[1];
  h[6] = (_Float16)f1[2]; h[7] = (_Float16)f1[3];
  *(half8*)(wh + i) = h;
}

// ---------------------------------------------------------------------------
// Fused kernel. Key change vs prev round: raw s_barrier with lgkmcnt(0) only
// (NO vmcnt drain) -> global prefetches stay in flight across k-phases.
// x prefetch distance = 2 phases (~1000 cyc > HBM latency). B-frags direct
// from L2, 1 phase ahead. One barrier per k-tile.
// ---------------------------------------------------------------------------
__device__ __forceinline__ void stage_a(_Float16* __restrict__ dst,
                                        float4_ x0, float4_ x1) {
  half8 h;
  h[0] = (_Float16)x0[0]; h[1] = (_Float16)x0[1];
  h[2] = (_Float16)x0[2]; h[3] = (_Float16)x0[3];
  h[4] = (_Float16)x1[0]; h[5] = (_Float16)x1[1];
  h[6] = (_Float16)x1[2]; h[7] = (_Float16)x1[3];
  *(half8*)dst = h;
}

// Publish LDS writes / retire LDS reads, then barrier. No vmcnt drain:
// outstanding global loads (x 2-ahead, B 1-ahead) survive the barrier.
#define PHASE_BARRIER() do {                              \
    __builtin_amdgcn_sched_barrier(0);                    \
    asm volatile("s_waitcnt lgkmcnt(0)" ::: "memory");    \
    __builtin_amdgcn_s_barrier();                         \
    __builtin_amdgcn_sched_barrier(0);                    \
  } while (0)

__global__ __launch_bounds__(NTH, 2) void fused_kernel(const float* __restrict__ x,
                                                       const _Float16* __restrict__ wh,
                                                       const float* __restrict__ bias,
                                                       float* __restrict__ out) {
  // A tile [32][64] halves, linear, 16B-granule XOR swizzle (granule g of row
  // r stored at g ^ (r&7)): bank-uniform on both b128 writes and b128 reads.
  __shared__ __align__(16) _Float16 As[2][BM * BK];   //  8192 B, double-buffered
  __shared__ __align__(16) float Ssh[BM][BN + 4];     // 16896 B (pad: 132f = 4-bank skew)
  __shared__ __align__(16) float bsh[16 * BN];        //  8192 B  (total 33280)

  const int tid  = threadIdx.x;
  const int wv   = tid >> 6;        // 0..3
  const int lane = tid & 63;
  const int l32  = lane & 31;
  const int hk   = lane >> 5;       // k-half within MFMA operand
  const int m0   = blockIdx.x * BM;
  const int nb   = blockIdx.y * BN; // 0 or 128

  // ---- bias -> LDS rep-major [16][BN] (published by prologue barrier) ----
  {
    const float4_* b4 = (const float4_*)bias;
    float4_* bs4 = (float4_*)bsh;
#pragma unroll
    for (int p = 0; p < 2; ++p) {
      int idx = p * NTH + tid;            // 0..511 float4
      int rep = idx >> 5, c4 = idx & 31;
      bs4[idx] = b4[rep * (N_DIM / 4) + (nb >> 2) + c4];
    }
  }

  // ---- A staging coords: thread t -> row t>>3, 16B granule t&7 ----
  const int arow = tid >> 3;
  const int ag   = tid & 7;
  const float* xg = x + (size_t)(m0 + arow) * K_DIM + ag * 8;
  _Float16* awr = &As[0][0] + arow * BK + ((ag ^ (arow & 7)) << 3);

  // ---- A-frag read base + swizzled granule offsets (g = ks*2 + hk) ----
  const _Float16* ard = &As[0][0] + l32 * BK;
  const int aoff0 = (((0 * 2 + hk) ^ (l32 & 7)) << 3);
  const int aoff1 = (((1 * 2 + hk) ^ (l32 & 7)) << 3);
  const int aoff2 = (((2 * 2 + hk) ^ (l32 & 7)) << 3);
  const int aoff3 = (((3 * 2 + hk) ^ (l32 & 7)) << 3);

  // ---- B-frag pointer: lane holds W[n = nb+wv*32+l32][k = hk*8 + j] ----
  const _Float16* wg = wh + (size_t)(nb + wv * 32 + l32) * K_DIM + hk * 8;

  f32x16 acc = {};

  // ---- prologue: tile0 staged; xE=tile1, xO=tile2 (2-phase distance); B0 ----
  float4_ t00 = *(const float4_*)(xg);
  float4_ t01 = *(const float4_*)(xg + 4);
  float4_ xE0 = *(const float4_*)(xg + BK);
  float4_ xE1 = *(const float4_*)(xg + BK + 4);
  float4_ xO0 = *(const float4_*)(xg + 2 * BK);
  float4_ xO1 = *(const float4_*)(xg + 2 * BK + 4);
  half8 bfA[4], bfB[4];
#pragma unroll
  for (int ks = 0; ks < 4; ++ks) bfA[ks] = *(const half8*)(wg + ks * 16);
  stage_a(awr, t00, t01);               // tile 0 -> As[0]
  PHASE_BARRIER();                      // As[0] + bsh published

  for (int kt = 0; kt < NKT; kt += 2) {
    // ---- even phase: compute tile kt (As[0], bfA); stage kt+1 -> As[1] ----
    {
      stage_a(awr + BM * BK, xE0, xE1);
      const int t3 = (kt + 3 < NKT ? kt + 3 : NKT - 1) * BK;
      xE0 = *(const float4_*)(xg + t3);
      xE1 = *(const float4_*)(xg + t3 + 4);
#pragma unroll
      for (int ks = 0; ks < 4; ++ks)
        bfB[ks] = *(const half8*)(wg + (kt + 1) * BK + ks * 16);
      half8 a0 = *(const half8*)(ard + aoff0);
      half8 a1 = *(const half8*)(ard + aoff1);
      half8 a2 = *(const half8*)(ard + aoff2);
      half8 a3 = *(const half8*)(ard + aoff3);
      __builtin_amdgcn_s_setprio(1);
      acc = __builtin_amdgcn_mfma_f32_32x32x16_f16(a0, bfA[0], acc, 0, 0, 0);
      acc = __builtin_amdgcn_mfma_f32_32x32x16_f16(a1, bfA[1], acc, 0, 0, 0);
      acc = __builtin_amdgcn_mfma_f32_32x32x16_f16(a2, bfA[2], acc, 0, 0, 0);
      acc = __builtin_amdgcn_mfma_f32_32x32x16_f16(a3, bfA[3], acc, 0, 0, 0);
      __builtin_amdgcn_s_setprio(0);
      PHASE_BARRIER();
    }
    // ---- odd phase: compute tile kt+1 (As[1], bfB); stage kt+2 -> As[0] ----
    {
      if (kt + 2 < NKT) stage_a(awr, xO0, xO1);
      const int t4 = (kt + 4 < NKT ? kt + 4 : NKT - 1) * BK;
      xO0 = *(const float4_*)(xg + t4);
      xO1 = *(const float4_*)(xg + t4 + 4);
      const int tB = (kt + 2 < NKT ? kt + 2 : NKT - 1) * BK;
#pragma unroll
      for (int ks = 0; ks < 4; ++ks)
        bfA[ks] = *(const half8*)(wg + tB + ks * 16);
      const _Float16* rd = ard + BM * BK;
      half8 a0 = *(const half8*)(rd + aoff0);
      half8 a1 = *(const half8*)(rd + aoff1);
      half8 a2 = *(const half8*)(rd + aoff2);
      half8 a3 = *(const half8*)(rd + aoff3);
      __builtin_amdgcn_s_setprio(1);
      acc = __builtin_amdgcn_mfma_f32_32x32x16_f16(a0, bfB[0], acc, 0, 0, 0);
      acc = __builtin_amdgcn_mfma_f32_32x32x16_f16(a1, bfB[1], acc, 0, 0, 0);
      acc = __builtin_amdgcn_mfma_f32_32x32x16_f16(a2, bfB[2], acc, 0, 0, 0);
      acc = __builtin_amdgcn_mfma_f32_32x32x16_f16(a3, bfB[3], acc, 0, 0, 0);
      __builtin_amdgcn_s_setprio(0);
      PHASE_BARRIER();
    }
  }

  // ---- epilogue 1: acc -> Ssh (C/D 32x32: col n = l32, row m per formula) ----
#pragma unroll
  for (int r = 0; r < 16; ++r) {
    const int m = (r & 3) + 8 * (r >> 2) + 4 * hk;
    Ssh[m][wv * 32 + l32] = acc[r];
  }
  __syncthreads();

  // ---- epilogue 2: out = S[m][j&255] + bias[j]; wave w owns rows w*8..+8 ----
  const float4_* bs4 = (const float4_*)bsh;
  const int c4 = l32;  // float4 col within BN
#pragma unroll
  for (int ri = 0; ri < 8; ++ri) {
    const int row = wv * 8 + ri;
    float4_ sv = *(const float4_*)(&Ssh[row][c4 * 4]);  // lanes 32-63: broadcast
    float* orow = out + (size_t)(m0 + row) * OUT_F + nb;
#pragma unroll
    for (int rr = 0; rr < 8; ++rr) {
      const int rep = rr * 2 + hk;
      float4_ bv = bs4[rep * (BN / 4) + c4];
      __builtin_nontemporal_store(sv + bv, (float4_*)(orow + rep * N_DIM) + c4);
    }
  }
}

// ---------------------------------------------------------------------------
extern "C" void kernel_launch(void* const* d_in, const int* in_sizes, int n_in,
                              void* d_out, int out_size, void* d_ws, size_t ws_size,
                              hipStream_t stream) {
  const float* x    = (const float*)d_in[0];
  const float* w    = (const float*)d_in[1];
  const float* bias = (const float*)d_in[2];
  float* out        = (float*)d_out;
  _Float16* wh      = (_Float16*)d_ws;  // 2 MB only

  convert_w_kernel<<<(N_DIM * K_DIM) / (256 * 8), 256, 0, stream>>>(w, wh);
  fused_kernel<<<dim3(M_DIM / BM, 2), NTH, 0, stream>>>(x, wh, bias, out);
}

// Round 4
// 282.753 us; speedup vs baseline: 1.0047x; 1.0047x over previous
//
#include <hip/hip_runtime.h>
#include <cstdint>
#include <cstddef>

// Problem constants
#define M_DIM 8192   // batch
#define N_DIM 256    // shared rows (distinct output cols)
#define K_DIM 4096   // in_features
#define OUT_F 4096   // out_features = 16 * N_DIM
// Fused GEMM tiling (R2 geometry: proven 0 bank conflicts, occ 38%)
#define BM 32        // m-rows per block
#define BN 128       // n-half per block -> grid (256,2) = 512 blocks = 2/CU
#define BK 64        // k per tile
#define NTH 512      // 8 waves; wave w owns 32m x 16n (Rm=1: zero B redundancy)
#define NKT (K_DIM / BK)  // 64

typedef float    float4_ __attribute__((ext_vector_type(4)));
typedef _Float16 half8   __attribute__((ext_vector_type(8)));
typedef _Float16 half4   __attribute__((ext_vector_type(4)));

// ---------------------------------------------------------------------------
// Kernel 1: convert shared_weights fp32 -> f16 (2 MB, stays L2-resident)
// ---------------------------------------------------------------------------
__global__ __launch_bounds__(256) void convert_w_kernel(const float* __restrict__ w,
                                                        _Float16* __restrict__ wh) {
  int i = (blockIdx.x * 256 + threadIdx.x) * 8;
  float4_ f0 = *(const float4_*)(w + i);
  float4_ f1 = *(const float4_*)(w + i + 4);
  half8 h;
  h[0] = (_Float16)f0[0]; h[1] = (_Float16)f0[1];
  h[2] = (_Float16)f0[2]; h[3] = (_Float16)f0[3];
  h[4] = (_Float16)f1[0]; h[5] = (_Float16)f1[1];
  h[6] = (_Float16)f1[2]; h[7] = (_Float16)f1[3];
  *(half8*)(wh + i) = h;
}

// ---------------------------------------------------------------------------
// Fused kernel. R2 structure; K-loop barrier = lgkmcnt(0)-only (NO vmcnt
// drain): x (2-phase distance, nontemporal) and B (1-phase distance, L2-hit)
// prefetches stay in flight across barriers; compiler inserts counted vmcnt
// waits at the register consumers.
// ---------------------------------------------------------------------------
__device__ __forceinline__ void load_bfrag(half8 b[2], const _Float16* __restrict__ wg,
                                           int kk) {
  b[0] = *(const half8*)(wg + kk);        // ks=0 granule
  b[1] = *(const half8*)(wg + kk + 32);   // ks=1 granule
}

// A tile [32][64] halves, linear, 16B-granule XOR swizzle (granule g of row r
// stored at g ^ (r&7)): bank-uniform on both writes and b128 reads (R2: 0 cf).
__device__ __forceinline__ void stage_a(_Float16* __restrict__ As, int arow, int asw,
                                        float4_ a) {
  half4 h;
  h[0] = (_Float16)a[0]; h[1] = (_Float16)a[1];
  h[2] = (_Float16)a[2]; h[3] = (_Float16)a[3];
  *(half4*)(As + arow * BK + asw) = h;
}

__device__ __forceinline__ void mfma_step(float4_ acc[2], const half8 b[2],
                                          const _Float16* __restrict__ As,
                                          int l16, int quad) {
  __builtin_amdgcn_s_setprio(1);
#pragma unroll
  for (int ks = 0; ks < 2; ++ks) {
    const int off = ((ks * 4 + quad) ^ (l16 & 7)) << 3;  // swizzled k-granule
    half8 a0 = *(const half8*)(As + l16 * BK + off);
    half8 a1 = *(const half8*)(As + (16 + l16) * BK + off);
    acc[0] = __builtin_amdgcn_mfma_f32_16x16x32_f16(a0, b[ks], acc[0], 0, 0, 0);
    acc[1] = __builtin_amdgcn_mfma_f32_16x16x32_f16(a1, b[ks], acc[1], 0, 0, 0);
  }
  __builtin_amdgcn_s_setprio(0);
}

// Publish LDS writes / retire LDS reads, then barrier. No vmcnt drain:
// outstanding global prefetches survive the barrier (the whole point).
#define PHASE_BARRIER() do {                              \
    __builtin_amdgcn_sched_barrier(0);                    \
    asm volatile("s_waitcnt lgkmcnt(0)" ::: "memory");    \
    __builtin_amdgcn_s_barrier();                         \
    __builtin_amdgcn_sched_barrier(0);                    \
  } while (0)

__global__ __launch_bounds__(NTH, 4) void fused_kernel(const float* __restrict__ x,
                                                       const _Float16* __restrict__ wh,
                                                       const float* __restrict__ bias,
                                                       float* __restrict__ out) {
  __shared__ __align__(16) _Float16 As[2][BM * BK];   //  8192 B, double-buffered
  __shared__ __align__(16) float Ssh[BM][BN + 4];     // 16896 B (pad: 4-bank skew)
  __shared__ __align__(16) float bsh[16 * BN];        //  8192 B  (total 33280)

  const int tid  = threadIdx.x;
  const int wv   = tid >> 6;        // 0..7
  const int lane = tid & 63;
  const int quad = lane >> 4;       // 0..3
  const int l16  = lane & 15;
  const int m0   = blockIdx.x * BM;
  const int nb   = blockIdx.y * BN; // 0 or 128; (bx,0)/(bx,1) land on same XCD

  // ---- bias -> LDS rep-major [16][BN] (published by prologue barrier) ----
  {
    const float4_* b4 = (const float4_*)bias;
    float4_* bs4 = (float4_*)bsh;
    int rep = tid >> 5, c4 = tid & 31;
    bs4[tid] = b4[rep * (N_DIM / 4) + (nb >> 2) + c4];
  }

  // ---- A staging coords: 32 rows x 64 f32 per kt; 512 thr x 1 float4 ----
  const int arow = tid >> 4;           // 0..31
  const int ac4  = tid & 15;           // float4 index 0..15
  const int asw  = ((((ac4 >> 1) ^ (arow & 7)) << 3) | ((ac4 & 1) << 2));
  const float* xg = x + (size_t)(m0 + arow) * K_DIM + ac4 * 4;

  // ---- B-frag pointer (per-lane, direct from L2-resident wh; Rm=1) ----
  const _Float16* wg = wh + (size_t)(nb + wv * 16 + l16) * K_DIM + quad * 8;

  float4_ acc[2];
  acc[0] = (float4_){0.f, 0.f, 0.f, 0.f};
  acc[1] = (float4_){0.f, 0.f, 0.f, 0.f};

  // ---- prologue: x 2 k-tiles ahead (nontemporal), B 1 k-tile ahead ----
  half8 bA[2], bB[2];
  float4_ aP0 = __builtin_nontemporal_load((const float4_*)(xg));
  float4_ aP1 = __builtin_nontemporal_load((const float4_*)(xg + BK));
  load_bfrag(bA, wg, 0);
  stage_a(As[0], arow, asw, aP0);
  aP0 = __builtin_nontemporal_load((const float4_*)(xg + 2 * BK));
  PHASE_BARRIER();  // As[0] + bsh published

  for (int kt = 0; kt < NKT; kt += 2) {
    // even: compute tile kt (As[0], bA); stage kt+1 -> As[1]
    load_bfrag(bB, wg, (kt + 1) * BK);             // B for next phase: max slack
    stage_a(As[1], arow, asw, aP1);
    if (kt + 3 < NKT)
      aP1 = __builtin_nontemporal_load((const float4_*)(xg + (kt + 3) * BK));
    mfma_step(acc, bA, As[0], l16, quad);
    PHASE_BARRIER();  // As[1] ready, As[0] free; vmem stays in flight

    // odd: compute tile kt+1 (As[1], bB); stage kt+2 -> As[0]
    if (kt + 2 < NKT) {
      load_bfrag(bA, wg, (kt + 2) * BK);
      stage_a(As[0], arow, asw, aP0);
      if (kt + 4 < NKT)
        aP0 = __builtin_nontemporal_load((const float4_*)(xg + (kt + 4) * BK));
    }
    mfma_step(acc, bB, As[1], l16, quad);
    PHASE_BARRIER();  // As[0] ready, As[1] free
  }

  // ---- epilogue 1: S-tile -> LDS (C/D layout: n=l16, m=quad*4+r) ----
#pragma unroll
  for (int mf = 0; mf < 2; ++mf)
#pragma unroll
    for (int r = 0; r < 4; ++r)
      Ssh[mf * 16 + quad * 4 + r][wv * 16 + l16] = acc[mf][r];
  PHASE_BARRIER();

  // ---- epilogue 2: out = S[m][j&255] + bias[j]; 512B-coalesced stores ----
  float4_* out4 = (float4_*)out;
  const float4_* bs4 = (const float4_*)bsh;
#pragma unroll
  for (int p = 0; p < 2; ++p) {
    const int row = wv * 4 + p * 2 + (lane >> 5);  // wave owns 4 m-rows
    const int c4  = lane & 31;                     // float4 col within 128-wide
    float4_ sv = *(const float4_*)(&Ssh[row][c4 * 4]);
    const size_t obase = (size_t)(m0 + row) * (OUT_F / 4) + (nb >> 2);
#pragma unroll
    for (int rep = 0; rep < 16; ++rep)
      __builtin_nontemporal_store(sv + bs4[rep * (BN / 4) + c4],
                                  out4 + obase + rep * (N_DIM / 4) + c4);
  }
}

// ---------------------------------------------------------------------------
extern "C" void kernel_launch(void* const* d_in, const int* in_sizes, int n_in,
                              void* d_out, int out_size, void* d_ws, size_t ws_size,
                              hipStream_t stream) {
  const float* x    = (const float*)d_in[0];
  const float* w    = (const float*)d_in[1];
  const float* bias = (const float*)d_in[2];
  float* out        = (float*)d_out;
  _Float16* wh      = (_Float16*)d_ws;  // 2 MB only

  convert_w_kernel<<<(N_DIM * K_DIM) / (256 * 8), 256, 0, stream>>>(w, wh);
  fused_kernel<<<dim3(M_DIM / BM, 2), NTH, 0, stream>>>(x, wh, bias, out);
}